// Round 1
// baseline (13.710 us; speedup 1.0000x reference)
//
#include <hip/hip_runtime.h>
#include <hip/hip_bf16.h>

#define CMPSWAP(a, b) { float _t = fminf(a, b); (b) = fmaxf(a, b); (a) = _t; }

__device__ __forceinline__ float median9(float p0, float p1, float p2,
                                         float p3, float p4, float p5,
                                         float p6, float p7, float p8) {
    // Classic 19-exchange median-of-9 network (Smith, "Implementing median filters")
    CMPSWAP(p1, p2); CMPSWAP(p4, p5); CMPSWAP(p7, p8);
    CMPSWAP(p0, p1); CMPSWAP(p3, p4); CMPSWAP(p6, p7);
    CMPSWAP(p1, p2); CMPSWAP(p4, p5); CMPSWAP(p7, p8);
    CMPSWAP(p0, p3); CMPSWAP(p5, p8); CMPSWAP(p4, p7);
    CMPSWAP(p3, p6); CMPSWAP(p1, p4); CMPSWAP(p2, p5);
    CMPSWAP(p4, p7); CMPSWAP(p4, p2); CMPSWAP(p6, p4);
    CMPSWAP(p4, p2);
    return p4;
}

__global__ void __launch_bounds__(256)
mad_kernel(const float* __restrict__ x, float* __restrict__ out) {
    const int W = 512;
    const int total = 8 * 512 * 512;
    int idx = blockIdx.x * blockDim.x + threadIdx.x;
    if (idx >= total) return;

    int px = idx & 511;
    int py = (idx >> 9) & 511;
    int b  = idx >> 18;

    // center channel (index 1 of 3)
    const float* base = x + ((size_t)(b * 3 + 1)) * (512 * 512);

    // reflect padding (numpy 'reflect': -1 -> 1, H -> H-2)
    int ym = (py == 0)   ? 1   : py - 1;
    int yp = (py == 511) ? 510 : py + 1;
    int xm = (px == 0)   ? 1   : px - 1;
    int xp = (px == 511) ? 510 : px + 1;

    const float* r0 = base + ym * W;
    const float* r1 = base + py * W;
    const float* r2 = base + yp * W;

    float v0 = r0[xm], v1 = r0[px], v2 = r0[xp];
    float v3 = r1[xm], v4 = r1[px], v5 = r1[xp];
    float v6 = r2[xm], v7 = r2[px], v8 = r2[xp];

    float med = median9(v0, v1, v2, v3, v4, v5, v6, v7, v8);

    float a0 = fabsf(v0 - med), a1 = fabsf(v1 - med), a2 = fabsf(v2 - med);
    float a3 = fabsf(v3 - med), a4 = fabsf(v4 - med), a5 = fabsf(v5 - med);
    float a6 = fabsf(v6 - med), a7 = fabsf(v7 - med), a8 = fabsf(v8 - med);

    float mad = median9(a0, a1, a2, a3, a4, a5, a6, a7, a8);

    out[idx] = mad;
}

extern "C" void kernel_launch(void* const* d_in, const int* in_sizes, int n_in,
                              void* d_out, int out_size, void* d_ws, size_t ws_size,
                              hipStream_t stream) {
    const float* x = (const float*)d_in[0];
    float* out = (float*)d_out;
    const int total = 8 * 512 * 512;
    const int block = 256;
    const int grid = (total + block - 1) / block;
    mad_kernel<<<grid, block, 0, stream>>>(x, out);
}

// Round 2
// 11.557 us; speedup vs baseline: 1.1863x; 1.1863x over previous
//
#include <hip/hip_runtime.h>
#include <hip/hip_bf16.h>

#define CMPSWAP(a, b) { float _t = fminf(a, b); (b) = fmaxf(a, b); (a) = _t; }

__device__ __forceinline__ float median9(float p0, float p1, float p2,
                                         float p3, float p4, float p5,
                                         float p6, float p7, float p8) {
    // Classic 19-exchange median-of-9 network
    CMPSWAP(p1, p2); CMPSWAP(p4, p5); CMPSWAP(p7, p8);
    CMPSWAP(p0, p1); CMPSWAP(p3, p4); CMPSWAP(p6, p7);
    CMPSWAP(p1, p2); CMPSWAP(p4, p5); CMPSWAP(p7, p8);
    CMPSWAP(p0, p3); CMPSWAP(p5, p8); CMPSWAP(p4, p7);
    CMPSWAP(p3, p6); CMPSWAP(p1, p4); CMPSWAP(p2, p5);
    CMPSWAP(p4, p7); CMPSWAP(p4, p2); CMPSWAP(p6, p4);
    CMPSWAP(p4, p2);
    return p4;
}

__device__ __forceinline__ float mad9(float v0, float v1, float v2,
                                      float v3, float v4, float v5,
                                      float v6, float v7, float v8) {
    float med = median9(v0, v1, v2, v3, v4, v5, v6, v7, v8);
    return median9(fabsf(v0 - med), fabsf(v1 - med), fabsf(v2 - med),
                   fabsf(v3 - med), fabsf(v4 - med), fabsf(v5 - med),
                   fabsf(v6 - med), fabsf(v7 - med), fabsf(v8 - med));
}

// 4 pixels per thread: per row one aligned float4 + left/right edge scalars.
__global__ void __launch_bounds__(256)
mad_kernel(const float* __restrict__ x, float* __restrict__ out) {
    const int W = 512;
    int idx = blockIdx.x * blockDim.x + threadIdx.x;   // 4-pixel group id
    // total groups = 8 * 512 * 128 = 524288
    int g  = idx & 127;          // group within row
    int py = (idx >> 7) & 511;   // row
    int b  = idx >> 16;          // batch
    int px0 = g << 2;            // first pixel column

    const float* base = x + ((size_t)(b * 3 + 1)) * (512 * 512);

    // reflect rows: -1 -> 1, 512 -> 510
    int ym = (py == 0)   ? 1   : py - 1;
    int yp = (py == 511) ? 510 : py + 1;

    const float* r0 = base + ym * W;
    const float* r1 = base + py * W;
    const float* r2 = base + yp * W;

    // reflect cols for the two edge scalars
    int xl = (px0 == 0)   ? 1   : px0 - 1;   // left neighbor of pixel px0
    int xr = (px0 == 508) ? 510 : px0 + 4;   // right neighbor of pixel px0+3

    float4 c0 = *reinterpret_cast<const float4*>(r0 + px0);
    float4 c1 = *reinterpret_cast<const float4*>(r1 + px0);
    float4 c2 = *reinterpret_cast<const float4*>(r2 + px0);
    float l0 = r0[xl], l1 = r1[xl], l2 = r2[xl];
    float q0 = r0[xr], q1 = r1[xr], q2 = r2[xr];

    float4 o;
    o.x = mad9(l0,   c0.x, c0.y,  l1,   c1.x, c1.y,  l2,   c2.x, c2.y);
    o.y = mad9(c0.x, c0.y, c0.z,  c1.x, c1.y, c1.z,  c2.x, c2.y, c2.z);
    o.z = mad9(c0.y, c0.z, c0.w,  c1.y, c1.z, c1.w,  c2.y, c2.z, c2.w);
    o.w = mad9(c0.z, c0.w, q0,    c1.z, c1.w, q1,    c2.z, c2.w, q2);

    *reinterpret_cast<float4*>(out + ((size_t)idx << 2)) = o;
}

extern "C" void kernel_launch(void* const* d_in, const int* in_sizes, int n_in,
                              void* d_out, int out_size, void* d_ws, size_t ws_size,
                              hipStream_t stream) {
    const float* x = (const float*)d_in[0];
    float* out = (float*)d_out;
    const int groups = 8 * 512 * 128;   // 4 pixels per thread
    const int block = 256;
    const int grid = groups / block;    // 2048 blocks
    mad_kernel<<<grid, block, 0, stream>>>(x, out);
}

// Round 3
// 11.424 us; speedup vs baseline: 1.2001x; 1.0116x over previous
//
#include <hip/hip_runtime.h>
#include <hip/hip_bf16.h>

__device__ __forceinline__ void ce(float& a, float& b) {
    float t = fminf(a, b); b = fmaxf(a, b); a = t;
}
__device__ __forceinline__ void s3(float& a, float& b, float& c) {
    ce(a, b); ce(a, c); ce(b, c);
}

// Batcher odd-even merge of sorted pair (x0<=x1) with y -> p0<=p1<=p2
__device__ __forceinline__ void merge21(float x0, float x1, float y0,
                                        float& p0, float& p1, float& p2) {
    ce(x0, y0);
    p0 = x0; p1 = y0; p2 = x1; ce(p1, p2);
}

// merge sorted triples (a0<=a1<=a2),(b0<=b1<=b2) -> w0..w5
__device__ __forceinline__ void merge33(float a0, float a1, float a2,
                                        float b0, float b1, float b2,
                                        float& w0, float& w1, float& w2,
                                        float& w3, float& w4, float& w5) {
    float x0 = a0, x1 = a2, y0 = b0, y1 = b2;
    ce(x0, y0); ce(x1, y1); ce(x1, y0);   // odds merged: x0,x1,y0,y1 sorted
    float e0 = a1, e1 = b1; ce(e0, e1);   // evens merged
    w0 = x0;
    w1 = x1; w2 = e0; ce(w1, w2);
    w3 = y0; w4 = e1; ce(w3, w4);
    w5 = y1;
}

// merge sorted-6 (c0..c5) with sorted-3 (d0..d2) -> w0..w8 (full sorted 9)
__device__ __forceinline__ void merge63(float c0, float c1, float c2, float c3, float c4, float c5,
                                        float d0, float d1, float d2,
                                        float& w0, float& w1, float& w2, float& w3, float& w4,
                                        float& w5, float& w6, float& w7, float& w8) {
    // odds: (c0,c2,c4) + (d0,d2) -> o0..o4  [merge32]
    float p0, p1, p2; merge21(c0, c4, d0, p0, p1, p2);
    float q0 = c2, q1 = d2; ce(q0, q1);
    float o0 = p0, o1 = p1, o2 = q0; ce(o1, o2);
    float o3 = p2, o4 = q1; ce(o3, o4);
    // evens: (c1,c3,c5) + (d1) -> e0..e3  [merge31]
    float r0, r1, r2; merge21(c1, c5, d1, r0, r1, r2);
    float e0 = r0, e1 = r1, e2 = c3; ce(e1, e2);
    float e3 = r2;
    // cleanup interleave
    w0 = o0;
    w1 = o1; w2 = e0; ce(w1, w2);
    w3 = o2; w4 = e1; ce(w3, w4);
    w5 = o3; w6 = e2; ce(w5, w6);
    w7 = o4; w8 = e3; ce(w7, w8);
}

// MAD from a sorted 9: devs around median m=w4 form two sorted 4-runs.
// MAD = 5th smallest of {0, a1..a4, b1..b4} = 4th smallest of runs
//     = max_i min(a_i, b_{5-i}).
__device__ __forceinline__ float mad_sorted9(float w0, float w1, float w2, float w3, float w4,
                                             float w5, float w6, float w7, float w8) {
    float m = w4;
    float m0 = fminf(m - w3, w8 - m);
    float m1 = fminf(m - w2, w7 - m);
    float m2 = fminf(m - w1, w6 - m);
    float m3 = fminf(m - w0, w5 - m);
    return fmaxf(fmaxf(m0, m1), fmaxf(m2, m3));
}

// pixel MAD given its left-pair merged sorted-6 and remaining sorted-3 column
__device__ __forceinline__ float mad_px(float c0, float c1, float c2, float c3, float c4, float c5,
                                        float d0, float d1, float d2) {
    float w0, w1, w2, w3, w4, w5, w6, w7, w8;
    merge63(c0, c1, c2, c3, c4, c5, d0, d1, d2, w0, w1, w2, w3, w4, w5, w6, w7, w8);
    return mad_sorted9(w0, w1, w2, w3, w4, w5, w6, w7, w8);
}

__global__ void __launch_bounds__(256)
mad_kernel(const float* __restrict__ x, float* __restrict__ out) {
    const int W = 512;
    int idx = blockIdx.x * blockDim.x + threadIdx.x;   // 4-pixel group id
    int g  = idx & 127;
    int py = (idx >> 7) & 511;
    int b  = idx >> 16;
    int px0 = g << 2;

    const float* base = x + ((size_t)(b * 3 + 1)) * (512 * 512);

    int ym = (py == 0)   ? 1   : py - 1;
    int yp = (py == 511) ? 510 : py + 1;

    const float* r0 = base + ym * W;
    const float* r1 = base + py * W;
    const float* r2 = base + yp * W;

    int xl = (px0 == 0)   ? 1   : px0 - 1;
    int xr = (px0 == 508) ? 510 : px0 + 4;

    float4 c0 = *reinterpret_cast<const float4*>(r0 + px0);
    float4 c1 = *reinterpret_cast<const float4*>(r1 + px0);
    float4 c2 = *reinterpret_cast<const float4*>(r2 + px0);
    float l0 = r0[xl], l1 = r1[xl], l2 = r2[xl];
    float q0 = r0[xr], q1 = r1[xr], q2 = r2[xr];

    // 6 shared column sorts (local cols: xl, px0..px0+3, xr)
    float A0 = l0,   A1 = l1,   A2 = l2;   s3(A0, A1, A2);   // col0
    float B0 = c0.x, B1 = c1.x, B2 = c2.x; s3(B0, B1, B2);   // col1
    float C0 = c0.y, C1 = c1.y, C2 = c2.y; s3(C0, C1, C2);   // col2
    float D0 = c0.z, D1 = c1.z, D2 = c2.z; s3(D0, D1, D2);   // col3
    float E0 = c0.w, E1 = c1.w, E2 = c2.w; s3(E0, E1, E2);   // col4
    float F0 = q0,   F1 = q1,   F2 = q2;   s3(F0, F1, F2);   // col5

    // shared pair merges: (0,1), (2,3), (4,5)
    float M01_0, M01_1, M01_2, M01_3, M01_4, M01_5;
    merge33(A0, A1, A2, B0, B1, B2, M01_0, M01_1, M01_2, M01_3, M01_4, M01_5);
    float M23_0, M23_1, M23_2, M23_3, M23_4, M23_5;
    merge33(C0, C1, C2, D0, D1, D2, M23_0, M23_1, M23_2, M23_3, M23_4, M23_5);
    float M45_0, M45_1, M45_2, M45_3, M45_4, M45_5;
    merge33(E0, E1, E2, F0, F1, F2, M45_0, M45_1, M45_2, M45_3, M45_4, M45_5);

    float4 o;
    o.x = mad_px(M01_0, M01_1, M01_2, M01_3, M01_4, M01_5, C0, C1, C2); // cols 0,1,2
    o.y = mad_px(M23_0, M23_1, M23_2, M23_3, M23_4, M23_5, B0, B1, B2); // cols 1,2,3
    o.z = mad_px(M23_0, M23_1, M23_2, M23_3, M23_4, M23_5, E0, E1, E2); // cols 2,3,4
    o.w = mad_px(M45_0, M45_1, M45_2, M45_3, M45_4, M45_5, D0, D1, D2); // cols 3,4,5

    *reinterpret_cast<float4*>(out + ((size_t)idx << 2)) = o;
}

extern "C" void kernel_launch(void* const* d_in, const int* in_sizes, int n_in,
                              void* d_out, int out_size, void* d_ws, size_t ws_size,
                              hipStream_t stream) {
    const float* x = (const float*)d_in[0];
    float* out = (float*)d_out;
    const int groups = 8 * 512 * 128;   // 4 pixels per thread
    const int block = 256;
    const int grid = groups / block;    // 2048 blocks
    mad_kernel<<<grid, block, 0, stream>>>(x, out);
}

// Round 4
// 10.638 us; speedup vs baseline: 1.2888x; 1.0739x over previous
//
#include <hip/hip_runtime.h>
#include <hip/hip_bf16.h>

__device__ __forceinline__ void ce(float& a, float& b) {
    float t = fminf(a, b); b = fmaxf(a, b); a = t;
}
__device__ __forceinline__ void s3(float& a, float& b, float& c) {
    ce(a, b); ce(a, c); ce(b, c);
}

// Batcher odd-even merge of sorted pair (x0<=x1) with y -> p0<=p1<=p2
__device__ __forceinline__ void merge21(float x0, float x1, float y0,
                                        float& p0, float& p1, float& p2) {
    ce(x0, y0);
    p0 = x0; p1 = y0; p2 = x1; ce(p1, p2);
}

// merge sorted triples -> w0..w5
__device__ __forceinline__ void merge33(float a0, float a1, float a2,
                                        float b0, float b1, float b2,
                                        float& w0, float& w1, float& w2,
                                        float& w3, float& w4, float& w5) {
    float x0 = a0, x1 = a2, y0 = b0, y1 = b2;
    ce(x0, y0); ce(x1, y1); ce(x1, y0);
    float e0 = a1, e1 = b1; ce(e0, e1);
    w0 = x0;
    w1 = x1; w2 = e0; ce(w1, w2);
    w3 = y0; w4 = e1; ce(w3, w4);
    w5 = y1;
}

// merge sorted-6 with sorted-3 -> full sorted 9
__device__ __forceinline__ void merge63(float c0, float c1, float c2, float c3, float c4, float c5,
                                        float d0, float d1, float d2,
                                        float& w0, float& w1, float& w2, float& w3, float& w4,
                                        float& w5, float& w6, float& w7, float& w8) {
    float p0, p1, p2; merge21(c0, c4, d0, p0, p1, p2);
    float q0 = c2, q1 = d2; ce(q0, q1);
    float o0 = p0, o1 = p1, o2 = q0; ce(o1, o2);
    float o3 = p2, o4 = q1; ce(o3, o4);
    float r0, r1, r2; merge21(c1, c5, d1, r0, r1, r2);
    float e0 = r0, e1 = r1, e2 = c3; ce(e1, e2);
    float e3 = r2;
    w0 = o0;
    w1 = o1; w2 = e0; ce(w1, w2);
    w3 = o2; w4 = e1; ce(w3, w4);
    w5 = o3; w6 = e2; ce(w5, w6);
    w7 = o4; w8 = e3; ce(w7, w8);
}

// MAD from sorted 9: devs form two sorted 4-runs around m=w4.
// MAD = 4th smallest of the runs = max_i min(a_i, b_{5-i}).
__device__ __forceinline__ float mad_sorted9(float w0, float w1, float w2, float w3, float w4,
                                             float w5, float w6, float w7, float w8) {
    float m = w4;
    float m0 = fminf(m - w3, w8 - m);
    float m1 = fminf(m - w2, w7 - m);
    float m2 = fminf(m - w1, w6 - m);
    float m3 = fminf(m - w0, w5 - m);
    return fmaxf(fmaxf(m0, m1), fmaxf(m2, m3));
}

__device__ __forceinline__ float mad_px(const float* pm, const float* d) {
    float w0, w1, w2, w3, w4, w5, w6, w7, w8;
    merge63(pm[0], pm[1], pm[2], pm[3], pm[4], pm[5], d[0], d[1], d[2],
            w0, w1, w2, w3, w4, w5, w6, w7, w8);
    return mad_sorted9(w0, w1, w2, w3, w4, w5, w6, w7, w8);
}

// One wave per image row: 64 lanes x 8 px. Halo via intra-wave shuffles.
__global__ void __launch_bounds__(256)
mad_kernel(const float* __restrict__ x, float* __restrict__ out) {
    const int W = 512;
    int lane = threadIdx.x & 63;
    int wid  = threadIdx.x >> 6;
    int rowg = blockIdx.x * 4 + wid;      // 0..4095 = b*512 + py
    int py = rowg & 511;

    const float* base = x + ((size_t)((rowg >> 9) * 3 + 1)) * (512 * 512);

    int ym = (py == 0)   ? 1   : py - 1;
    int yp = (py == 511) ? 510 : py + 1;

    const float* r0 = base + ym * W;
    const float* r1 = base + py * W;
    const float* r2 = base + yp * W;

    int c = lane << 3;   // 8 pixels per lane
    float4 a0 = *reinterpret_cast<const float4*>(r0 + c);
    float4 b0 = *reinterpret_cast<const float4*>(r0 + c + 4);
    float4 a1 = *reinterpret_cast<const float4*>(r1 + c);
    float4 b1 = *reinterpret_cast<const float4*>(r1 + c + 4);
    float4 a2 = *reinterpret_cast<const float4*>(r2 + c);
    float4 b2 = *reinterpret_cast<const float4*>(r2 + c + 4);

    // halo: left = prev lane's b.w (col c-1); right = next lane's a.x (col c+8)
    float L0 = __shfl_up(b0.w, 1), L1 = __shfl_up(b1.w, 1), L2 = __shfl_up(b2.w, 1);
    float R0 = __shfl_down(a0.x, 1), R1 = __shfl_down(a1.x, 1), R2 = __shfl_down(a2.x, 1);
    if (lane == 0)  { L0 = a0.y; L1 = a1.y; L2 = a2.y; }   // reflect: col -1 -> 1
    if (lane == 63) { R0 = b0.z; R1 = b1.z; R2 = b2.z; }   // reflect: col 512 -> 510

    // 10 column triples (halo-L, 8 pixel cols, halo-R), each sorted
    float col[10][3];
    col[0][0] = L0;   col[0][1] = L1;   col[0][2] = L2;
    col[1][0] = a0.x; col[1][1] = a1.x; col[1][2] = a2.x;
    col[2][0] = a0.y; col[2][1] = a1.y; col[2][2] = a2.y;
    col[3][0] = a0.z; col[3][1] = a1.z; col[3][2] = a2.z;
    col[4][0] = a0.w; col[4][1] = a1.w; col[4][2] = a2.w;
    col[5][0] = b0.x; col[5][1] = b1.x; col[5][2] = b2.x;
    col[6][0] = b0.y; col[6][1] = b1.y; col[6][2] = b2.y;
    col[7][0] = b0.z; col[7][1] = b1.z; col[7][2] = b2.z;
    col[8][0] = b0.w; col[8][1] = b1.w; col[8][2] = b2.w;
    col[9][0] = R0;   col[9][1] = R1;   col[9][2] = R2;
#pragma unroll
    for (int i = 0; i < 10; ++i) s3(col[i][0], col[i][1], col[i][2]);

    // 5 shared pair merges: (0,1),(2,3),(4,5),(6,7),(8,9)
    float pm[5][6];
#pragma unroll
    for (int i = 0; i < 5; ++i)
        merge33(col[2*i][0], col[2*i][1], col[2*i][2],
                col[2*i+1][0], col[2*i+1][1], col[2*i+1][2],
                pm[i][0], pm[i][1], pm[i][2], pm[i][3], pm[i][4], pm[i][5]);

    // pixel j uses cols (j, j+1, j+2): pair (j+1)>>1, extra col (j odd ? j : j+2)
    float o[8];
#pragma unroll
    for (int j = 0; j < 8; ++j) {
        const int pi = (j + 1) >> 1;
        const int ei = (j & 1) ? j : j + 2;
        o[j] = mad_px(pm[pi], col[ei]);
    }

    float* orow = out + (size_t)rowg * W + c;
    *reinterpret_cast<float4*>(orow)     = make_float4(o[0], o[1], o[2], o[3]);
    *reinterpret_cast<float4*>(orow + 4) = make_float4(o[4], o[5], o[6], o[7]);
}

extern "C" void kernel_launch(void* const* d_in, const int* in_sizes, int n_in,
                              void* d_out, int out_size, void* d_ws, size_t ws_size,
                              hipStream_t stream) {
    const float* x = (const float*)d_in[0];
    float* out = (float*)d_out;
    const int rows = 8 * 512;          // one wave per row
    const int block = 256;             // 4 waves per block
    const int grid = rows / 4;         // 1024 blocks
    mad_kernel<<<grid, block, 0, stream>>>(x, out);
}